// Round 12
// baseline (649.429 us; speedup 1.0000x reference)
//
#include <hip/hip_runtime.h>

#define BB 16
#define CC 256
#define NN 4096
#define MM 1024
#define EPSV 1e-5f
#define SCALE (1.0f/16.0f)   // 1/sqrt(C)

// ---- workspace layout (float offsets). Fixed part 23,499,776 floats = ~94 MB ----
#define OFF_MU    0            // 4096  (mu; dead after transpose_score -> reused: u[257], b2)
#define OFF_SCORE 4096         // 65536 (score; dead after select -> reused: beta [B][M])
#define OFF_IDX   69632        // 32768 ints (idx_s then idx_g)
#define OFF_U     102400       // 65536
#define OFF_WVZ   167936       // 65536
#define OFF_WF12  233472       // 65536 (Wf12 f32; dead after conv -> reused: W2)
#define OFF_BVZ   299008       // 256
#define OFF_BZ    299264       // 256
#define OFF_W16   299520       // 4 bf16 weight mats = 131072 floats
#define OFF_XG    430592       // Xg bf16 [16*1024][256] = 2097152 floats
#define OFF_K16   2527744      // K bf16 [B][M][C] = 2097152 floats
#define OFF_VT16  4624896      // Vt bf16 [B][C][M] = 2097152 floats
#define OFF_Z     6722048      // 16777216 floats
#define OFF_BN    23499264     // 512
#define FIXED_F   23499776     // end of fixed region (floats)

typedef __attribute__((ext_vector_type(8))) short s16x8;
typedef __attribute__((ext_vector_type(4))) float f32x4;

__device__ __forceinline__ unsigned short f2bf(float f) {
    unsigned int u = __float_as_uint(f);
    return (unsigned short)((u + 0x7FFFu + ((u >> 16) & 1u)) >> 16);
}
__device__ __forceinline__ float bf2f(unsigned short h) {
    return __uint_as_float(((unsigned int)h) << 16);
}

__global__ __launch_bounds__(256) void zero_bn_kernel(float* bn) {
    int t = threadIdx.x;
    bn[t] = 0.f; bn[t + CC] = 0.f;
}

__global__ __launch_bounds__(256) void zero_rsum_kernel(float* r) {
    r[blockIdx.x * 256 + threadIdx.x] = 0.f;
}

// mu[b,c] = mean over n of x[b,c,n]  (float4 loads, 4 iters/thread)
__global__ __launch_bounds__(256) void mean_kernel(const float* __restrict__ x, float* __restrict__ mu) {
    int c = blockIdx.x, b = blockIdx.y, t = threadIdx.x;
    const float4* p = (const float4*)(x + ((size_t)b * CC + c) * NN);
    float s = 0.f;
    for (int n = t; n < NN / 4; n += 256) { float4 v = p[n]; s += (v.x + v.y) + (v.z + v.w); }
    __shared__ float red[256];
    red[t] = s; __syncthreads();
    for (int w = 128; w > 0; w >>= 1) { if (t < w) red[t] += red[t + w]; __syncthreads(); }
    if (t == 0) mu[b * CC + c] = red[0] * (1.0f / NN);
}

// x [B][C][N] f32 -> xT16 [B][N][C] bf16, fused with score accumulation
__global__ __launch_bounds__(256) void transpose_score_kernel(const float* __restrict__ x,
                                                              const float* __restrict__ mu,
                                                              unsigned short* __restrict__ xT,
                                                              float* __restrict__ score) {
    __shared__ float tile[32][33];
    __shared__ float smu[32];
    int b = blockIdx.z, c0 = blockIdx.y * 32, n0 = blockIdx.x * 32, t = threadIdx.x;
    int nl = t & 31, cr = t >> 5;
    if (t < 32) smu[t] = mu[b * CC + c0 + t];
#pragma unroll
    for (int q = 0; q < 4; ++q)
        tile[cr + q * 8][nl] = x[((size_t)b * CC + c0 + cr + q * 8) * NN + n0 + nl];
    __syncthreads();
    int nr = t >> 3, cq = t & 7;
    uint2 p;
    p.x = (unsigned int)f2bf(tile[cq * 4 + 0][nr]) | ((unsigned int)f2bf(tile[cq * 4 + 1][nr]) << 16);
    p.y = (unsigned int)f2bf(tile[cq * 4 + 2][nr]) | ((unsigned int)f2bf(tile[cq * 4 + 3][nr]) << 16);
    *(uint2*)&xT[((size_t)b * NN + n0 + nr) * CC + c0 + cq * 4] = p;
    int n = t & 31, cseg = t >> 5;
    float part = 0.f;
#pragma unroll
    for (int q = 0; q < 4; ++q) {
        float d = tile[cseg * 4 + q][n] - smu[cseg * 4 + q];
        part += d * d;
    }
    __syncthreads();
    tile[n][cseg] = part;
    __syncthreads();
    if (t < 32) {
        float s = 0.f;
#pragma unroll
        for (int j = 0; j < 8; ++j) s += tile[t][j];
        atomicAdd(&score[(size_t)b * NN + n0 + t], s);
    }
}

// radix-select: per batch, top-1024 set -> idx_s, bottom-1024 set -> idx_g (order arbitrary)
__global__ __launch_bounds__(1024) void select_kernel(const float* __restrict__ score,
                                                      int* __restrict__ idx_s, int* __restrict__ idx_g) {
    int b = blockIdx.x, t = threadIdx.x;
    __shared__ unsigned int keys[NN];
    __shared__ unsigned int hist[256];
    __shared__ unsigned int sbin, skrem;
    __shared__ int outcnt, eqcnt;
    __shared__ int eqidx[NN];
    for (int q = t; q < NN; q += 1024) keys[q] = __float_as_uint(score[(size_t)b * NN + q]);
    __syncthreads();
    for (int r = 0; r < 2; ++r) {
        unsigned int flip = r ? 0xFFFFFFFFu : 0u;
        unsigned int prefix = 0u, pmask = 0u;
        unsigned int k = MM;
        for (int pass = 0; pass < 4; ++pass) {
            int shift = 24 - 8 * pass;
            if (t < 256) hist[t] = 0u;
            __syncthreads();
            for (int q = t; q < NN; q += 1024) {
                unsigned int kv = keys[q] ^ flip;
                if ((kv & pmask) == prefix) atomicAdd(&hist[(kv >> shift) & 255u], 1u);
            }
            __syncthreads();
            for (int off = 1; off < 256; off <<= 1) {
                unsigned int v = 0u;
                if (t < 256) v = hist[t] + ((t + off < 256) ? hist[t + off] : 0u);
                __syncthreads();
                if (t < 256) hist[t] = v;
                __syncthreads();
            }
            if (t < 256) {
                unsigned int sj = hist[t], sj1 = (t < 255) ? hist[t + 1] : 0u;
                if (sj >= k && sj1 < k) { sbin = (unsigned int)t; skrem = k - sj1; }
            }
            __syncthreads();
            prefix |= sbin << shift;
            pmask |= 0xFFu << shift;
            k = skrem;
            __syncthreads();
        }
        unsigned int T = prefix;
        unsigned int krem = k;
        int* outp = r ? idx_g : idx_s;
        if (t == 0) { outcnt = 0; eqcnt = 0; }
        __syncthreads();
        for (int q = t; q < NN; q += 1024) {
            unsigned int kv = keys[q] ^ flip;
            if (kv > T) { int pp = atomicAdd(&outcnt, 1); outp[(size_t)b * MM + pp] = q; }
            else if (kv == T) { int pp = atomicAdd(&eqcnt, 1); eqidx[pp] = q; }
        }
        __syncthreads();
        int ne = eqcnt;
        for (int i = t; i < ne; i += 1024) {
            int me = eqidx[i];
            int rank = 0;
            for (int j = 0; j < ne; ++j) rank += (eqidx[j] < me) ? 1 : 0;
            if (rank < (int)krem) { int pp = atomicAdd(&outcnt, 1); outp[(size_t)b * MM + pp] = me; }
        }
        __syncthreads();
    }
}

__global__ __launch_bounds__(256) void smallmm_kernel(const float* __restrict__ A, int lda, int aoff,
                                                      const float* __restrict__ Bm, float* __restrict__ Cm) {
    int e = blockIdx.x, t = threadIdx.x;
    __shared__ float arow[CC];
    arow[t] = A[e * lda + aoff + t];
    __syncthreads();
    float acc = 0.f;
    for (int k = 0; k < CC; ++k) acc += arow[k] * Bm[k * CC + t];
    Cm[e * CC + t] = acc;
}

__global__ __launch_bounds__(256) void bvz_kernel(const float* __restrict__ U, const float* __restrict__ bv,
                                                  float* __restrict__ bvz) {
    int e = threadIdx.x;
    float acc = 0.f;
    for (int d = 0; d < CC; ++d) acc += U[e * CC + d] * bv[d];
    bvz[e] = acc;
}

__global__ __launch_bounds__(256) void bz_kernel(const float* __restrict__ Wf, const float* __restrict__ bf,
                                                 const float* __restrict__ bo_s, const float* __restrict__ bo_g,
                                                 float* __restrict__ bz) {
    int e = threadIdx.x;
    float acc = bf[e];
    for (int c = 0; c < CC; ++c)
        acc += Wf[e * 2 * CC + c] * bo_s[c] + Wf[e * 2 * CC + CC + c] * bo_g[c];
    bz[e] = acc;
}

__global__ __launch_bounds__(256) void wf12_kernel(const float* __restrict__ Wf, float* __restrict__ Wf12) {
    int e = blockIdx.x, c = threadIdx.x;
    Wf12[e * CC + c] = Wf[e * 2 * CC + c] + Wf[e * 2 * CC + CC + c];
}

// W2[d][e] = sum_c Wq[c][d] * Wk[c][e]   (Q-fold: S = xT·K''^T + beta)
__global__ __launch_bounds__(256) void w2_kernel(const float* __restrict__ Wq, const float* __restrict__ Wk,
                                                 float* __restrict__ W2) {
    int d = blockIdx.x, t = threadIdx.x;
    __shared__ float aq[CC];
    aq[t] = Wq[t * CC + d];
    __syncthreads();
    float acc = 0.f;
    for (int c = 0; c < CC; ++c) acc += aq[c] * Wk[c * CC + t];
    W2[d * CC + t] = acc;
}

// u[e] = sum_c bq[c]*Wk[c][e]; u[256] = bq·bk; b2[d] = sum_c Wq[c][d]*bk[c]
__global__ __launch_bounds__(256) void ub2_kernel(const float* __restrict__ Wq, const float* __restrict__ Wk,
                                                  const float* __restrict__ bq, const float* __restrict__ bk,
                                                  float* __restrict__ u, float* __restrict__ b2) {
    int t = threadIdx.x;
    float au = 0.f, ab = 0.f;
    for (int c = 0; c < CC; ++c) { au += bq[c] * Wk[c * CC + t]; ab += Wq[c * CC + t] * bk[c]; }
    u[t] = au; b2[t] = ab;
    if (t == 0) { float s = 0.f; for (int c = 0; c < CC; ++c) s += bq[c] * bk[c]; u[CC] = s; }
}

// beta[row] = Xg[row]·u + u[256]   (one wave per row)
__global__ __launch_bounds__(256) void beta_kernel(const unsigned short* __restrict__ Xg,
                                                   const float* __restrict__ u, float* __restrict__ beta) {
    int row = blockIdx.x * 4 + (threadIdx.x >> 6);
    int l = threadIdx.x & 63;
    uint2 p = *(const uint2*)&Xg[(size_t)row * CC + l * 4];
    float acc = bf2f((unsigned short)(p.x & 0xFFFF)) * u[l * 4]
              + bf2f((unsigned short)(p.x >> 16)) * u[l * 4 + 1]
              + bf2f((unsigned short)(p.y & 0xFFFF)) * u[l * 4 + 2]
              + bf2f((unsigned short)(p.y >> 16)) * u[l * 4 + 3];
    acc += __shfl_xor(acc, 1); acc += __shfl_xor(acc, 2); acc += __shfl_xor(acc, 4);
    acc += __shfl_xor(acc, 8); acc += __shfl_xor(acc, 16); acc += __shfl_xor(acc, 32);
    if (l == 0) beta[row] = acc + u[CC];
}

__global__ __launch_bounds__(256) void conv_bf16_kernel(const float* __restrict__ src,
                                                        unsigned short* __restrict__ dst) {
    int i = blockIdx.x * 256 + threadIdx.x;
    float4 v = *(const float4*)(src + (size_t)i * 4);
    uint2 p;
    p.x = (unsigned int)f2bf(v.x) | ((unsigned int)f2bf(v.y) << 16);
    p.y = (unsigned int)f2bf(v.z) | ((unsigned int)f2bf(v.w) << 16);
    *(uint2*)&dst[(size_t)i * 4] = p;
}

__global__ __launch_bounds__(256) void gather_kernel(const unsigned short* __restrict__ xT,
                                                     const int* __restrict__ idx,
                                                     unsigned short* __restrict__ Xg) {
    int row = blockIdx.x * 4 + (threadIdx.x >> 6);
    int l = threadIdx.x & 63;
    int b = row >> 10, m = row & (MM - 1);
    int src = idx[b * MM + m];
    *(uint2*)&Xg[(size_t)row * CC + l * 4] =
        *(const uint2*)&xT[((size_t)b * NN + src) * CC + l * 4];
}

// ---- generic bf16 MFMA GEMM: out[i][j] = sum_k A[i][k]*Bw[j][k] (+bias), 128x128 tile ----
template<int OMODE>
__global__ __launch_bounds__(256, 3) void gemm_bt(
    const unsigned short* __restrict__ A, size_t a_bs,
    const unsigned short* __restrict__ Bw, size_t b_bs,
    const float* __restrict__ bias,
    void* __restrict__ outp, size_t o_bs, int ldo)
{
    __shared__ __align__(16) unsigned short As[128 * 32];
    __shared__ __align__(16) unsigned short Bs[128 * 32];
    int z = blockIdx.z;
    const unsigned short* Ab = A + z * a_bs + (size_t)blockIdx.x * 128 * CC;
    const unsigned short* Bb = Bw + z * b_bs + (size_t)blockIdx.y * 128 * CC;
    int t = threadIdx.x, w = t >> 6, l = t & 63, g = l >> 4, c16 = l & 15;
    int wi = w >> 1, wj = w & 1;
    int srow = t >> 2, skq = (t & 3) * 8;

    f32x4 acc[4][4];
#pragma unroll
    for (int a = 0; a < 4; ++a)
#pragma unroll
        for (int bq = 0; bq < 4; ++bq) acc[a][bq] = (f32x4){0.f, 0.f, 0.f, 0.f};

    for (int ks = 0; ks < 8; ++ks) {
        int k0 = ks * 32;
        uint4 a0 = *(const uint4*)(Ab + (size_t)srow * CC + k0 + skq);
        uint4 a1 = *(const uint4*)(Ab + (size_t)(srow + 64) * CC + k0 + skq);
        uint4 b0 = *(const uint4*)(Bb + (size_t)srow * CC + k0 + skq);
        uint4 b1 = *(const uint4*)(Bb + (size_t)(srow + 64) * CC + k0 + skq);
        __syncthreads();
        *(uint4*)&As[srow * 32 + skq] = a0;
        *(uint4*)&As[(srow + 64) * 32 + skq] = a1;
        *(uint4*)&Bs[srow * 32 + skq] = b0;
        *(uint4*)&Bs[(srow + 64) * 32 + skq] = b1;
        __syncthreads();
        s16x8 af[4], bf4[4];
#pragma unroll
        for (int fi = 0; fi < 4; ++fi)
            af[fi] = *(const s16x8*)&As[(wi * 64 + fi * 16 + c16) * 32 + g * 8];
#pragma unroll
        for (int fj = 0; fj < 4; ++fj)
            bf4[fj] = *(const s16x8*)&Bs[(wj * 64 + fj * 16 + c16) * 32 + g * 8];
#pragma unroll
        for (int fi = 0; fi < 4; ++fi)
#pragma unroll
            for (int fj = 0; fj < 4; ++fj)
                acc[fi][fj] = __builtin_amdgcn_mfma_f32_16x16x32_bf16(af[fi], bf4[fj], acc[fi][fj], 0, 0, 0);
    }

    int i0 = blockIdx.x * 128 + wi * 64, j0 = blockIdx.y * 128 + wj * 64;
#pragma unroll
    for (int fi = 0; fi < 4; ++fi) {
#pragma unroll
        for (int fj = 0; fj < 4; ++fj) {
            int colg = j0 + fj * 16 + c16;
#pragma unroll
            for (int r = 0; r < 4; ++r) {
                int rowg = i0 + fi * 16 + g * 4 + r;
                float v = acc[fi][fj][r] + (OMODE == 2 ? bias[rowg] : bias[colg]);
                if (OMODE == 0)
                    ((float*)outp)[z * o_bs + (size_t)rowg * ldo + colg] = v;
                else
                    ((unsigned short*)outp)[z * o_bs + (size_t)rowg * ldo + colg] = f2bf(v);
            }
        }
    }
}

// ---- fused flash-style attention: Z[z][n][e] += (exp((xT·K''^T + beta)/16)·V) / rsum[n] ----
// Round-10 1-barrier pipeline + Q-fold (Q-GEMM eliminated; per-column beta added in exp).
// V swizzle FIX (round 11 failed): generator must stay WITHIN the 64B row -> XOR bits
// 4-5 only, generator = er bits 1-2 (addr bits 7-8, untouched by the XOR = involution).
// Round 11's <<4 of a 3-bit gen hit addr bit 6 = V row-bit0, so the pre-XOR'd global
// source read bytes outside the tile's 64B row segment (wrong V data, absmax 4.8).
// Banks: (er&1, (er>>1)&3) -> 8 distinct groups per 16 lanes = 2-way (free).
__global__ __attribute__((amdgpu_flat_work_group_size(512, 512)))
__attribute__((amdgpu_waves_per_eu(2, 2)))
void fused_attn(
    const unsigned short* __restrict__ Q,    // xT [B][N][C] bf16
    const unsigned short* __restrict__ K,    // K'' [B][M][C] bf16 (b2 included)
    const unsigned short* __restrict__ Vt,   // [B][C][M] bf16 (bias included)
    const float* __restrict__ beta,          // [B][M]
    float* __restrict__ Z)                   // [B][N][C] +=
{
    extern __shared__ __align__(16) unsigned char smem[];
    // [K0 16K][K1 16K][V0 16K][V1 16K][V2 16K][P0 16K][P1 16K][rsl 1K][beta 4K] = 117 KB
    float* rsl = (float*)(smem + 114688);
    float* bs  = (float*)(smem + 115712);

    int z = blockIdx.z;
    int n0 = blockIdx.x * 128;
    int t = threadIdx.x, w = t >> 6, l = t & 63, g = l >> 4, c16 = l & 15;
    int wn = w >> 1, wc = w & 1;   // wave grid: 4 n-rows x 2 m/e-cols

    const unsigned short* Qb = Q + ((size_t)z * NN + n0) * CC;
    const char* Kzb = (const char*)(K + (size_t)z * MM * CC);
    const char* Vzb = (const char*)(Vt + (size_t)z * CC * MM);

    // beta table -> LDS (visible after prologue __syncthreads)
    bs[t] = beta[(size_t)z * MM + t];
    bs[t + 512] = beta[(size_t)z * MM + t + 512];

    // Q fragments: rows wn*32 + fi*16 + c16, k = ks*32 + g*8  (64 VGPR)
    s16x8 q[2][8];
#pragma unroll
    for (int fi = 0; fi < 2; ++fi)
#pragma unroll
        for (int ks = 0; ks < 8; ++ks)
            q[fi][ks] = *(const s16x8*)&Qb[(size_t)(wn * 32 + fi * 16 + c16) * CC + ks * 32 + g * 8];

    f32x4 o[2][8];
#pragma unroll
    for (int fi = 0; fi < 2; ++fi)
#pragma unroll
        for (int fj = 0; fj < 8; ++fj) o[fi][fj] = (f32x4){0.f, 0.f, 0.f, 0.f};
    float rs[2][4];
#pragma unroll
    for (int fi = 0; fi < 2; ++fi)
#pragma unroll
        for (int r = 0; r < 4; ++r) rs[fi][r] = 0.f;

    // gll staging (LDS linear, global source pre-XOR'd). K tile 16KB: 32 rows x 512B.
    auto issueK = [&](int buf, int m0) {
#pragma unroll
        for (int j = 0; j < 2; ++j) {
            int cid = w * 2 + j;
            int row = cid * 2 + (l >> 5);
            int srcoff = ((l & 31) * 16) ^ ((row & 7) << 4);
            const char* gp = Kzb + (size_t)(m0 + row) * 512 + srcoff;
            __builtin_amdgcn_global_load_lds(
                (const __attribute__((address_space(1))) void*)gp,
                (__attribute__((address_space(3))) void*)(smem + buf * 16384 + cid * 1024),
                16, 0, 0);
        }
    };
    // V tile 16KB: 256 rows x 64B; swizzle ^(((row>>1)&3)<<4) — bits 4-5 only (in-row)
    auto issueV = [&](int slot, int m0) {
#pragma unroll
        for (int j = 0; j < 2; ++j) {
            int cid = w * 2 + j;
            int row = cid * 16 + (l >> 2);
            int srcoff = ((l & 3) * 16) ^ (((row >> 1) & 3) << 4);
            const char* gp = Vzb + (size_t)row * 2048 + (size_t)m0 * 2 + srcoff;
            __builtin_amdgcn_global_load_lds(
                (const __attribute__((address_space(1))) void*)gp,
                (__attribute__((address_space(3))) void*)(smem + 32768 + slot * 16384 + cid * 1024),
                16, 0, 0);
        }
    };

    // QK(t)+exp -> P[par]. sacc: n-row = wn*32+fi*16+g*4+r, m = m0 + wc*16 + c16.
    auto qk_exp = [&](int buf, int par, int m0) {
        const unsigned char* Ks = smem + buf * 16384;
        unsigned char* Ps = smem + 81920 + par * 16384;
        f32x4 sacc[2];
#pragma unroll
        for (int fi = 0; fi < 2; ++fi) sacc[fi] = (f32x4){0.f, 0.f, 0.f, 0.f};
        int mr = wc * 16 + c16;
        __builtin_amdgcn_s_setprio(1);
#pragma unroll
        for (int ks = 0; ks < 8; ++ks) {
            s16x8 kf = *(const s16x8*)(Ks + ((mr * 512 + ks * 64 + g * 16) ^ ((mr & 7) << 4)));
#pragma unroll
            for (int fi = 0; fi < 2; ++fi)
                sacc[fi] = __builtin_amdgcn_mfma_f32_16x16x32_bf16(q[fi][ks], kf, sacc[fi], 0, 0, 0);
        }
        __builtin_amdgcn_s_setprio(0);
        float bet = bs[m0 + wc * 16 + c16];
#pragma unroll
        for (int fi = 0; fi < 2; ++fi)
#pragma unroll
            for (int r = 0; r < 4; ++r) {
                float e = __expf((sacc[fi][r] + bet) * SCALE);
                unsigned short h = f2bf(e);
                int nr = wn * 32 + fi * 16 + g * 4 + r;
                *(unsigned short*)(Ps + ((nr * 128 + (wc * 16 + c16) * 2) ^ ((nr & 7) << 4))) = h;
                rs[fi][r] += bf2f(h);
            }
    };
    // PV(t): O += P[par] · V[slot]
    auto pv = [&](int slot, int par) {
        const unsigned char* Vs = smem + 32768 + slot * 16384;
        const unsigned char* Ps = smem + 81920 + par * 16384;
        s16x8 pa[2];
#pragma unroll
        for (int fi = 0; fi < 2; ++fi) {
            int nr = wn * 32 + fi * 16 + c16;
            pa[fi] = *(const s16x8*)(Ps + ((nr * 128 + g * 16) ^ ((nr & 7) << 4)));
        }
        __builtin_amdgcn_s_setprio(1);
#pragma unroll
        for (int fj = 0; fj < 8; ++fj) {
            int er = wc * 128 + fj * 16 + c16;
            s16x8 vb = *(const s16x8*)(Vs + ((er * 64 + g * 16) ^ (((er >> 1) & 3) << 4)));
#pragma unroll
            for (int fi = 0; fi < 2; ++fi)
                o[fi][fj] = __builtin_amdgcn_mfma_f32_16x16x32_bf16(pa[fi], vb, o[fi][fj], 0, 0, 0);
        }
        __builtin_amdgcn_s_setprio(0);
    };

    // prologue: stage tiles 0,1; compute QK(0)->P[0]
    issueK(0, 0); issueV(0, 0);
    issueK(1, 32); issueV(1, 32);
    __syncthreads();
    qk_exp(0, 0, 0);

    for (int mt = 0; mt < 32; ++mt) {
        __syncthreads();   // publishes P[mt&1]; drains gll issued last interval
        if (mt < 30) {
            issueK(mt & 1, (mt + 2) * 32);          // K[mt&1] held K(mt), consumed last interval
            issueV((mt + 2) % 3, (mt + 2) * 32);    // V slot held V(mt-1), read last interval
        }
        __builtin_amdgcn_sched_barrier(0);
        if (mt < 31) qk_exp((mt + 1) & 1, (mt + 1) & 1, (mt + 1) * 32);
        pv(mt % 3, mt & 1);
    }

    // cross-lane + cross-wave rsum
#pragma unroll
    for (int fi = 0; fi < 2; ++fi)
#pragma unroll
        for (int r = 0; r < 4; ++r) {
            float v = rs[fi][r];
            v += __shfl_xor(v, 1); v += __shfl_xor(v, 2);
            v += __shfl_xor(v, 4); v += __shfl_xor(v, 8);
            if (c16 == 0) rsl[wc * 128 + wn * 32 + fi * 16 + g * 4 + r] = v;
        }
    __syncthreads();
    float* Zb = Z + ((size_t)z * NN + n0) * CC;
#pragma unroll
    for (int fi = 0; fi < 2; ++fi)
#pragma unroll
        for (int r = 0; r < 4; ++r) {
            int nr = wn * 32 + fi * 16 + g * 4 + r;
            float inv = 1.0f / (rsl[nr] + rsl[128 + nr]);
#pragma unroll
            for (int fj = 0; fj < 8; ++fj) {
                int e = wc * 128 + fj * 16 + c16;
                Zb[(size_t)nr * CC + e] += o[fi][fj][r] * inv;
            }
        }
}

// BN stats: per-channel sum and sumsq over B*N rows of Z [B*N][C]
__global__ __launch_bounds__(256) void bn_stats_kernel(const float* __restrict__ Z, float* __restrict__ bn) {
    int blk = blockIdx.x, e = threadIdx.x;
    const float* p = Z + (size_t)blk * 256 * CC + e;
    float s1 = 0.f, s2 = 0.f;
    for (int r = 0; r < 256; ++r) { float v = p[(size_t)r * CC]; s1 += v; s2 += v * v; }
    atomicAdd(&bn[e], s1);
    atomicAdd(&bn[CC + e], s2);
}

// normalize + relu + transpose [B][N][C] -> [B][C][N]
__global__ __launch_bounds__(256) void bn_apply_kernel(const float* __restrict__ Z, const float* __restrict__ bn,
                                                       const float* __restrict__ gamma, const float* __restrict__ beta,
                                                       float* __restrict__ out) {
    int b = blockIdx.z, e0 = blockIdx.y * 32, n0 = blockIdx.x * 32, t = threadIdx.x;
    __shared__ float tile[32][33];
    int c = t & 31, r0 = (t >> 5) * 4;
#pragma unroll
    for (int q = 0; q < 4; ++q)
        tile[r0 + q][c] = Z[((size_t)b * NN + n0 + r0 + q) * CC + e0 + c];
    __syncthreads();
    int n = t & 31, er0 = (t >> 5) * 4;
    const float invcnt = 1.0f / (BB * NN);
#pragma unroll
    for (int q = 0; q < 4; ++q) {
        int e = e0 + er0 + q;
        float mean = bn[e] * invcnt;
        float var = bn[CC + e] * invcnt - mean * mean;
        float rsq = rsqrtf(var + EPSV);
        float v = (tile[n][er0 + q] - mean) * rsq * gamma[e] + beta[e];
        out[((size_t)b * CC + e) * NN + n0 + n] = fmaxf(v, 0.f);
    }
}

extern "C" void kernel_launch(void* const* d_in, const int* in_sizes, int n_in,
                              void* d_out, int out_size, void* d_ws, size_t ws_size,
                              hipStream_t stream) {
    const float* x    = (const float*)d_in[0];
    const float* Wq_s = (const float*)d_in[2];  const float* bq_s = (const float*)d_in[3];
    const float* Wk_s = (const float*)d_in[4];  const float* bk_s = (const float*)d_in[5];
    const float* Wv_s = (const float*)d_in[6];  const float* bv_s = (const float*)d_in[7];
    const float* Wo_s = (const float*)d_in[8];  const float* bo_s = (const float*)d_in[9];
    const float* Wq_g = (const float*)d_in[10]; const float* bq_g = (const float*)d_in[11];
    const float* Wk_g = (const float*)d_in[12]; const float* bk_g = (const float*)d_in[13];
    const float* Wv_g = (const float*)d_in[14]; const float* bv_g = (const float*)d_in[15];
    const float* Wo_g = (const float*)d_in[16]; const float* bo_g = (const float*)d_in[17];
    const float* Wf   = (const float*)d_in[18]; const float* bf   = (const float*)d_in[19];
    const float* gamma = (const float*)d_in[20]; const float* beta = (const float*)d_in[21];

    float* ws    = (float*)d_ws;
    float* mu    = ws + OFF_MU;
    float* score = ws + OFF_SCORE;
    int*   idx_s = (int*)(ws + OFF_IDX);
    int*   idx_g = idx_s + BB * MM;
    float* U     = ws + OFF_U;
    float* Wvz   = ws + OFF_WVZ;
    float* Wf12  = ws + OFF_WF12;
    float* bvz   = ws + OFF_BVZ;
    float* bz    = ws + OFF_BZ;
    float* W2    = ws + OFF_WF12;          // Wf12 f32 dead after its conv
    float* uvec  = ws + OFF_MU;            // mu dead after transpose_score; 257 floats
    float* b2    = ws + OFF_MU + 512;      // 256 floats
    float* betaA = ws + OFF_SCORE;         // score dead after select; [B][M] floats
    unsigned short* Wf12_16 = (unsigned short*)(ws + OFF_W16);
    unsigned short* W2_16   = Wf12_16 + 65536;
    unsigned short* Wvz16   = W2_16 + 65536;
    unsigned short* Xg16 = (unsigned short*)(ws + OFF_XG);
    unsigned short* K16  = (unsigned short*)(ws + OFF_K16);
    unsigned short* Vt16 = (unsigned short*)(ws + OFF_VT16);
    float* Z     = ws + OFF_Z;
    float* bn    = ws + OFF_BN;
    // d_out doubles as scratch: second half holds xT16 (dead before bn_apply writes)
    unsigned short* xT16 = (unsigned short*)d_out + (size_t)BB * NN * CC;

    zero_bn_kernel<<<1, 256, 0, stream>>>(bn);
    mean_kernel<<<dim3(CC, BB), 256, 0, stream>>>(x, mu);
    zero_rsum_kernel<<<BB * NN / 256, 256, 0, stream>>>(score);
    transpose_score_kernel<<<dim3(NN / 32, CC / 32, BB), 256, 0, stream>>>(x, mu, xT16, score);
    select_kernel<<<BB, 1024, 0, stream>>>(score, idx_s, idx_g);
    wf12_kernel<<<CC, 256, 0, stream>>>(Wf, Wf12);
    bz_kernel<<<1, 256, 0, stream>>>(Wf, bf, bo_s, bo_g, bz);
    conv_bf16_kernel<<<64, 256, 0, stream>>>(Wf12, Wf12_16);
    // Z = xT @ Wf12^T + bz  (residual x through both conv halves)
    gemm_bt<0><<<dim3(512, 2, 1), 256, 0, stream>>>(xT16, 0, Wf12_16, 0, bz, Z, 0, CC);

    for (int br = 0; br < 2; ++br) {
        const float* Wo = br ? Wo_g : Wo_s;
        const float* Wv = br ? Wv_g : Wv_s;  const float* bv = br ? bv_g : bv_s;
        const float* Wk = br ? Wk_g : Wk_s;  const float* bk = br ? bk_g : bk_s;
        const float* Wq = br ? Wq_g : Wq_s;  const float* bq = br ? bq_g : bq_s;
        int* idx = br ? idx_g : idx_s;
        int aoff = br ? CC : 0;
        // U = Wf_half @ Wo ; Wvz = U @ Wv ; bvz = U @ bv
        smallmm_kernel<<<CC, 256, 0, stream>>>(Wf, 2 * CC, aoff, Wo, U);
        smallmm_kernel<<<CC, 256, 0, stream>>>(U, CC, 0, Wv, Wvz);
        bvz_kernel<<<1, 256, 0, stream>>>(U, bv, bvz);
        // Q-fold precomputes: W2 = Wq^T-contracted Wk ; u, b2
        w2_kernel<<<CC, 256, 0, stream>>>(Wq, Wk, W2);
        ub2_kernel<<<1, 256, 0, stream>>>(Wq, Wk, bq, bk, uvec, b2);
        conv_bf16_kernel<<<64, 256, 0, stream>>>(W2, W2_16);
        conv_bf16_kernel<<<64, 256, 0, stream>>>(Wvz, Wvz16);
        // gather context rows once
        gather_kernel<<<BB * MM / 4, 256, 0, stream>>>(xT16, idx, Xg16);
        // K'' = Xg @ W2^T + b2 ; beta = Xg·u + bq·bk ; Vt = Wvz @ Xg^T + bvz
        gemm_bt<1><<<dim3(BB * MM / 128, 2, 1), 256, 0, stream>>>(Xg16, 0, W2_16, 0, b2, K16, 0, CC);
        beta_kernel<<<BB * MM / 4, 256, 0, stream>>>(Xg16, uvec, betaA);
        gemm_bt<2><<<dim3(2, 8, BB), 256, 0, stream>>>(Wvz16, 0, Xg16, (size_t)MM * CC, bvz,
                                                       Vt16, (size_t)CC * MM, MM);

        // fused flash attention: Z += softmax((xT·K''^T + beta)/16)·V
        fused_attn<<<dim3(NN / 128, 1, BB), 512, 119808, stream>>>(xT16, K16, Vt16, betaA, Z);
    }

    bn_stats_kernel<<<BB * NN / 256, 256, 0, stream>>>(Z, bn);
    bn_apply_kernel<<<dim3(NN / 32, CC / 32, BB), 256, 0, stream>>>(Z, bn, gamma, beta, (float*)d_out);
}

// Round 13
// 593.744 us; speedup vs baseline: 1.0938x; 1.0938x over previous
//
#include <hip/hip_runtime.h>

#define BB 16
#define CC 256
#define NN 4096
#define MM 1024
#define EPSV 1e-5f
#define SCALE (1.0f/16.0f)   // 1/sqrt(C)

// ---- workspace layout (float offsets). Fixed part 23,499,776 floats = ~94 MB ----
#define OFF_MU    0            // 4096  (mu; dead after transpose_score -> u[257], b2, wob)
#define OFF_SCORE 4096         // 65536 (score; dead after select -> beta [B][M])
#define OFF_IDX   69632        // 32768 ints (idx_s then idx_g)
#define OFF_U     102400       // 65536 (WoWv f32 scratch)
#define OFF_WVZ   167936       // 65536 (unused)
#define OFF_WF12  233472       // 65536 (Wf12 f32)
#define OFF_BVZ   299008       // 256
#define OFF_BZ    299264       // 256
#define OFF_W16   299520       // 4 bf16 weight mats = 131072 floats
#define OFF_XG    430592       // Xg bf16 [16*1024][256] = 2097152 floats
#define OFF_K16   2527744      // K bf16 [B][M][C] = 2097152 floats
#define OFF_VT16  4624896      // Vt bf16 [B][C][M] = 2097152 floats
#define OFF_Z     6722048      // 16777216 floats
#define OFF_BN    23499264     // 512
#define FIXED_F   23499776     // end of fixed region (floats)

typedef __attribute__((ext_vector_type(8))) short s16x8;
typedef __attribute__((ext_vector_type(4))) float f32x4;

__device__ __forceinline__ unsigned short f2bf(float f) {
    unsigned int u = __float_as_uint(f);
    return (unsigned short)((u + 0x7FFFu + ((u >> 16) & 1u)) >> 16);
}
__device__ __forceinline__ float bf2f(unsigned short h) {
    return __uint_as_float(((unsigned int)h) << 16);
}

__global__ __launch_bounds__(256) void zero_bn_kernel(float* bn) {
    int t = threadIdx.x;
    bn[t] = 0.f; bn[t + CC] = 0.f;
}

__global__ __launch_bounds__(256) void zero_rsum_kernel(float* r) {
    r[blockIdx.x * 256 + threadIdx.x] = 0.f;
}

// mu[b,c] = mean over n of x[b,c,n]  (float4 loads, 4 iters/thread)
__global__ __launch_bounds__(256) void mean_kernel(const float* __restrict__ x, float* __restrict__ mu) {
    int c = blockIdx.x, b = blockIdx.y, t = threadIdx.x;
    const float4* p = (const float4*)(x + ((size_t)b * CC + c) * NN);
    float s = 0.f;
    for (int n = t; n < NN / 4; n += 256) { float4 v = p[n]; s += (v.x + v.y) + (v.z + v.w); }
    __shared__ float red[256];
    red[t] = s; __syncthreads();
    for (int w = 128; w > 0; w >>= 1) { if (t < w) red[t] += red[t + w]; __syncthreads(); }
    if (t == 0) mu[b * CC + c] = red[0] * (1.0f / NN);
}

// x [B][C][N] f32 -> xT16 [B][N][C] bf16, fused with score accumulation
__global__ __launch_bounds__(256) void transpose_score_kernel(const float* __restrict__ x,
                                                              const float* __restrict__ mu,
                                                              unsigned short* __restrict__ xT,
                                                              float* __restrict__ score) {
    __shared__ float tile[32][33];
    __shared__ float smu[32];
    int b = blockIdx.z, c0 = blockIdx.y * 32, n0 = blockIdx.x * 32, t = threadIdx.x;
    int nl = t & 31, cr = t >> 5;
    if (t < 32) smu[t] = mu[b * CC + c0 + t];
#pragma unroll
    for (int q = 0; q < 4; ++q)
        tile[cr + q * 8][nl] = x[((size_t)b * CC + c0 + cr + q * 8) * NN + n0 + nl];
    __syncthreads();
    int nr = t >> 3, cq = t & 7;
    uint2 p;
    p.x = (unsigned int)f2bf(tile[cq * 4 + 0][nr]) | ((unsigned int)f2bf(tile[cq * 4 + 1][nr]) << 16);
    p.y = (unsigned int)f2bf(tile[cq * 4 + 2][nr]) | ((unsigned int)f2bf(tile[cq * 4 + 3][nr]) << 16);
    *(uint2*)&xT[((size_t)b * NN + n0 + nr) * CC + c0 + cq * 4] = p;
    int n = t & 31, cseg = t >> 5;
    float part = 0.f;
#pragma unroll
    for (int q = 0; q < 4; ++q) {
        float d = tile[cseg * 4 + q][n] - smu[cseg * 4 + q];
        part += d * d;
    }
    __syncthreads();
    tile[n][cseg] = part;
    __syncthreads();
    if (t < 32) {
        float s = 0.f;
#pragma unroll
        for (int j = 0; j < 8; ++j) s += tile[t][j];
        atomicAdd(&score[(size_t)b * NN + n0 + t], s);
    }
}

// radix-select: per batch, top-1024 set -> idx_s, bottom-1024 set -> idx_g (order arbitrary)
__global__ __launch_bounds__(1024) void select_kernel(const float* __restrict__ score,
                                                      int* __restrict__ idx_s, int* __restrict__ idx_g) {
    int b = blockIdx.x, t = threadIdx.x;
    __shared__ unsigned int keys[NN];
    __shared__ unsigned int hist[256];
    __shared__ unsigned int sbin, skrem;
    __shared__ int outcnt, eqcnt;
    __shared__ int eqidx[NN];
    for (int q = t; q < NN; q += 1024) keys[q] = __float_as_uint(score[(size_t)b * NN + q]);
    __syncthreads();
    for (int r = 0; r < 2; ++r) {
        unsigned int flip = r ? 0xFFFFFFFFu : 0u;
        unsigned int prefix = 0u, pmask = 0u;
        unsigned int k = MM;
        for (int pass = 0; pass < 4; ++pass) {
            int shift = 24 - 8 * pass;
            if (t < 256) hist[t] = 0u;
            __syncthreads();
            for (int q = t; q < NN; q += 1024) {
                unsigned int kv = keys[q] ^ flip;
                if ((kv & pmask) == prefix) atomicAdd(&hist[(kv >> shift) & 255u], 1u);
            }
            __syncthreads();
            for (int off = 1; off < 256; off <<= 1) {
                unsigned int v = 0u;
                if (t < 256) v = hist[t] + ((t + off < 256) ? hist[t + off] : 0u);
                __syncthreads();
                if (t < 256) hist[t] = v;
                __syncthreads();
            }
            if (t < 256) {
                unsigned int sj = hist[t], sj1 = (t < 255) ? hist[t + 1] : 0u;
                if (sj >= k && sj1 < k) { sbin = (unsigned int)t; skrem = k - sj1; }
            }
            __syncthreads();
            prefix |= sbin << shift;
            pmask |= 0xFFu << shift;
            k = skrem;
            __syncthreads();
        }
        unsigned int T = prefix;
        unsigned int krem = k;
        int* outp = r ? idx_g : idx_s;
        if (t == 0) { outcnt = 0; eqcnt = 0; }
        __syncthreads();
        for (int q = t; q < NN; q += 1024) {
            unsigned int kv = keys[q] ^ flip;
            if (kv > T) { int pp = atomicAdd(&outcnt, 1); outp[(size_t)b * MM + pp] = q; }
            else if (kv == T) { int pp = atomicAdd(&eqcnt, 1); eqidx[pp] = q; }
        }
        __syncthreads();
        int ne = eqcnt;
        for (int i = t; i < ne; i += 1024) {
            int me = eqidx[i];
            int rank = 0;
            for (int j = 0; j < ne; ++j) rank += (eqidx[j] < me) ? 1 : 0;
            if (rank < (int)krem) { int pp = atomicAdd(&outcnt, 1); outp[(size_t)b * MM + pp] = me; }
        }
        __syncthreads();
    }
}

__global__ __launch_bounds__(256) void bz_kernel(const float* __restrict__ Wf, const float* __restrict__ bf,
                                                 const float* __restrict__ bo_s, const float* __restrict__ bo_g,
                                                 float* __restrict__ bz) {
    int e = threadIdx.x;
    float acc = bf[e];
    for (int c = 0; c < CC; ++c)
        acc += Wf[e * 2 * CC + c] * bo_s[c] + Wf[e * 2 * CC + CC + c] * bo_g[c];
    bz[e] = acc;
}

__global__ __launch_bounds__(256) void wf12_kernel(const float* __restrict__ Wf, float* __restrict__ Wf12) {
    int e = blockIdx.x, c = threadIdx.x;
    Wf12[e * CC + c] = Wf[e * 2 * CC + c] + Wf[e * 2 * CC + CC + c];
}

// ---- branch precompute, consolidated (replaces smallmm x2, bvz, w2, ub2, conv x2) ----
// y=0: WoWv[k][t] = sum_d Wo[k][d]*Wv[d][t]              (f32 scratch)
// y=1: W2[d][t]   = sum_c Wq[c][d]*Wk[c][t]  -> bf16     (Q-fold weight)
// y=2 (block x=0): wob[k]=Wo[k]·bv; u[t]=bq·Wk[:,t]; b2[d]=Wq[:,d]·bk; u[256]=bq·bk
__global__ __launch_bounds__(256) void prep1_kernel(
    const float* __restrict__ Wo, const float* __restrict__ Wv,
    const float* __restrict__ Wq, const float* __restrict__ Wk,
    const float* __restrict__ bq, const float* __restrict__ bk, const float* __restrict__ bv,
    float* __restrict__ WoWv, unsigned short* __restrict__ W2_16,
    float* __restrict__ wob, float* __restrict__ u, float* __restrict__ b2)
{
    int xr = blockIdx.x, y = blockIdx.y, t = threadIdx.x;
    if (y == 0) {
        __shared__ float arow[CC];
        arow[t] = Wo[xr * CC + t];
        __syncthreads();
        float acc = 0.f;
        for (int k = 0; k < CC; ++k) acc += arow[k] * Wv[k * CC + t];
        WoWv[xr * CC + t] = acc;
    } else if (y == 1) {
        __shared__ float aq[CC];
        aq[t] = Wq[t * CC + xr];
        __syncthreads();
        float acc = 0.f;
        for (int c = 0; c < CC; ++c) acc += aq[c] * Wk[c * CC + t];
        W2_16[xr * CC + t] = f2bf(acc);
    } else if (xr == 0) {
        float a1 = 0.f, a2 = 0.f, a3 = 0.f;
        for (int c = 0; c < CC; ++c) {
            a1 += Wo[t * CC + c] * bv[c];
            a2 += bq[c] * Wk[c * CC + t];
            a3 += Wq[c * CC + t] * bk[c];
        }
        wob[t] = a1; u[t] = a2; b2[t] = a3;
        if (t == 0) { float s = 0.f; for (int c = 0; c < CC; ++c) s += bq[c] * bk[c]; u[CC] = s; }
    }
}

// Wvz[e][t] = sum_k Wf_half[e][k]*WoWv[k][t] -> bf16 ; bvz[e] = Wf_half[e]·wob
// (re-association: Wvz = Wf·(Wo·Wv), bvz = Wf·(Wo·bv) — U never materialized)
__global__ __launch_bounds__(256) void prep2_kernel(
    const float* __restrict__ Wf, int aoff, const float* __restrict__ WoWv,
    const float* __restrict__ wob, unsigned short* __restrict__ Wvz16, float* __restrict__ bvz)
{
    int e = blockIdx.x, t = threadIdx.x;
    __shared__ float arow[CC];
    __shared__ float red[256];
    arow[t] = Wf[e * 2 * CC + aoff + t];
    __syncthreads();
    float acc = 0.f;
    for (int k = 0; k < CC; ++k) acc += arow[k] * WoWv[k * CC + t];
    Wvz16[e * CC + t] = f2bf(acc);
    red[t] = arow[t] * wob[t];
    __syncthreads();
    for (int w = 128; w > 0; w >>= 1) { if (t < w) red[t] += red[t + w]; __syncthreads(); }
    if (t == 0) bvz[e] = red[0];
}

// beta[row] = Xg[row]·u + u[256]   (one wave per row)
__global__ __launch_bounds__(256) void beta_kernel(const unsigned short* __restrict__ Xg,
                                                   const float* __restrict__ u, float* __restrict__ beta) {
    int row = blockIdx.x * 4 + (threadIdx.x >> 6);
    int l = threadIdx.x & 63;
    uint2 p = *(const uint2*)&Xg[(size_t)row * CC + l * 4];
    float acc = bf2f((unsigned short)(p.x & 0xFFFF)) * u[l * 4]
              + bf2f((unsigned short)(p.x >> 16)) * u[l * 4 + 1]
              + bf2f((unsigned short)(p.y & 0xFFFF)) * u[l * 4 + 2]
              + bf2f((unsigned short)(p.y >> 16)) * u[l * 4 + 3];
    acc += __shfl_xor(acc, 1); acc += __shfl_xor(acc, 2); acc += __shfl_xor(acc, 4);
    acc += __shfl_xor(acc, 8); acc += __shfl_xor(acc, 16); acc += __shfl_xor(acc, 32);
    if (l == 0) beta[row] = acc + u[CC];
}

__global__ __launch_bounds__(256) void conv_bf16_kernel(const float* __restrict__ src,
                                                        unsigned short* __restrict__ dst) {
    int i = blockIdx.x * 256 + threadIdx.x;
    float4 v = *(const float4*)(src + (size_t)i * 4);
    uint2 p;
    p.x = (unsigned int)f2bf(v.x) | ((unsigned int)f2bf(v.y) << 16);
    p.y = (unsigned int)f2bf(v.z) | ((unsigned int)f2bf(v.w) << 16);
    *(uint2*)&dst[(size_t)i * 4] = p;
}

__global__ __launch_bounds__(256) void gather_kernel(const unsigned short* __restrict__ xT,
                                                     const int* __restrict__ idx,
                                                     unsigned short* __restrict__ Xg) {
    int row = blockIdx.x * 4 + (threadIdx.x >> 6);
    int l = threadIdx.x & 63;
    int b = row >> 10, m = row & (MM - 1);
    int src = idx[b * MM + m];
    *(uint2*)&Xg[(size_t)row * CC + l * 4] =
        *(const uint2*)&xT[((size_t)b * NN + src) * CC + l * 4];
}

// ---- generic bf16 MFMA GEMM: out[i][j] = sum_k A[i][k]*Bw[j][k] (+bias), 128x128 tile ----
template<int OMODE>
__global__ __launch_bounds__(256, 3) void gemm_bt(
    const unsigned short* __restrict__ A, size_t a_bs,
    const unsigned short* __restrict__ Bw, size_t b_bs,
    const float* __restrict__ bias,
    void* __restrict__ outp, size_t o_bs, int ldo)
{
    __shared__ __align__(16) unsigned short As[128 * 32];
    __shared__ __align__(16) unsigned short Bs[128 * 32];
    int z = blockIdx.z;
    const unsigned short* Ab = A + z * a_bs + (size_t)blockIdx.x * 128 * CC;
    const unsigned short* Bb = Bw + z * b_bs + (size_t)blockIdx.y * 128 * CC;
    int t = threadIdx.x, w = t >> 6, l = t & 63, g = l >> 4, c16 = l & 15;
    int wi = w >> 1, wj = w & 1;
    int srow = t >> 2, skq = (t & 3) * 8;

    f32x4 acc[4][4];
#pragma unroll
    for (int a = 0; a < 4; ++a)
#pragma unroll
        for (int bq = 0; bq < 4; ++bq) acc[a][bq] = (f32x4){0.f, 0.f, 0.f, 0.f};

    for (int ks = 0; ks < 8; ++ks) {
        int k0 = ks * 32;
        uint4 a0 = *(const uint4*)(Ab + (size_t)srow * CC + k0 + skq);
        uint4 a1 = *(const uint4*)(Ab + (size_t)(srow + 64) * CC + k0 + skq);
        uint4 b0 = *(const uint4*)(Bb + (size_t)srow * CC + k0 + skq);
        uint4 b1 = *(const uint4*)(Bb + (size_t)(srow + 64) * CC + k0 + skq);
        __syncthreads();
        *(uint4*)&As[srow * 32 + skq] = a0;
        *(uint4*)&As[(srow + 64) * 32 + skq] = a1;
        *(uint4*)&Bs[srow * 32 + skq] = b0;
        *(uint4*)&Bs[(srow + 64) * 32 + skq] = b1;
        __syncthreads();
        s16x8 af[4], bf4[4];
#pragma unroll
        for (int fi = 0; fi < 4; ++fi)
            af[fi] = *(const s16x8*)&As[(wi * 64 + fi * 16 + c16) * 32 + g * 8];
#pragma unroll
        for (int fj = 0; fj < 4; ++fj)
            bf4[fj] = *(const s16x8*)&Bs[(wj * 64 + fj * 16 + c16) * 32 + g * 8];
#pragma unroll
        for (int fi = 0; fi < 4; ++fi)
#pragma unroll
            for (int fj = 0; fj < 4; ++fj)
                acc[fi][fj] = __builtin_amdgcn_mfma_f32_16x16x32_bf16(af[fi], bf4[fj], acc[fi][fj], 0, 0, 0);
    }

    int i0 = blockIdx.x * 128 + wi * 64, j0 = blockIdx.y * 128 + wj * 64;
#pragma unroll
    for (int fi = 0; fi < 4; ++fi) {
#pragma unroll
        for (int fj = 0; fj < 4; ++fj) {
            int colg = j0 + fj * 16 + c16;
#pragma unroll
            for (int r = 0; r < 4; ++r) {
                int rowg = i0 + fi * 16 + g * 4 + r;
                float v = acc[fi][fj][r] + (OMODE == 2 ? bias[rowg] : bias[colg]);
                if (OMODE == 0)
                    ((float*)outp)[z * o_bs + (size_t)rowg * ldo + colg] = v;
                else
                    ((unsigned short*)outp)[z * o_bs + (size_t)rowg * ldo + colg] = f2bf(v);
            }
        }
    }
}

// ---- fused flash-style attention: Z[z][n][e] += (exp((xT·K''^T + beta)/16)·V) / rsum[n] ----
// 1-barrier pipeline, gll staging, Q-fold, V swizzle in-row bits 4-5 (round 12, passing).
__global__ __attribute__((amdgpu_flat_work_group_size(512, 512)))
__attribute__((amdgpu_waves_per_eu(2, 2)))
void fused_attn(
    const unsigned short* __restrict__ Q,    // xT [B][N][C] bf16
    const unsigned short* __restrict__ K,    // K'' [B][M][C] bf16 (b2 included)
    const unsigned short* __restrict__ Vt,   // [B][C][M] bf16 (bias included)
    const float* __restrict__ beta,          // [B][M]
    float* __restrict__ Z)                   // [B][N][C] +=
{
    extern __shared__ __align__(16) unsigned char smem[];
    // [K0 16K][K1 16K][V0 16K][V1 16K][V2 16K][P0 16K][P1 16K][rsl 1K][beta 4K] = 117 KB
    float* rsl = (float*)(smem + 114688);
    float* bs  = (float*)(smem + 115712);

    int z = blockIdx.z;
    int n0 = blockIdx.x * 128;
    int t = threadIdx.x, w = t >> 6, l = t & 63, g = l >> 4, c16 = l & 15;
    int wn = w >> 1, wc = w & 1;   // wave grid: 4 n-rows x 2 m/e-cols

    const unsigned short* Qb = Q + ((size_t)z * NN + n0) * CC;
    const char* Kzb = (const char*)(K + (size_t)z * MM * CC);
    const char* Vzb = (const char*)(Vt + (size_t)z * CC * MM);

    // beta table -> LDS (visible after prologue __syncthreads)
    bs[t] = beta[(size_t)z * MM + t];
    bs[t + 512] = beta[(size_t)z * MM + t + 512];

    // Q fragments: rows wn*32 + fi*16 + c16, k = ks*32 + g*8  (64 VGPR)
    s16x8 q[2][8];
#pragma unroll
    for (int fi = 0; fi < 2; ++fi)
#pragma unroll
        for (int ks = 0; ks < 8; ++ks)
            q[fi][ks] = *(const s16x8*)&Qb[(size_t)(wn * 32 + fi * 16 + c16) * CC + ks * 32 + g * 8];

    f32x4 o[2][8];
#pragma unroll
    for (int fi = 0; fi < 2; ++fi)
#pragma unroll
        for (int fj = 0; fj < 8; ++fj) o[fi][fj] = (f32x4){0.f, 0.f, 0.f, 0.f};
    float rs[2][4];
#pragma unroll
    for (int fi = 0; fi < 2; ++fi)
#pragma unroll
        for (int r = 0; r < 4; ++r) rs[fi][r] = 0.f;

    // gll staging (LDS linear, global source pre-XOR'd). K tile 16KB: 32 rows x 512B.
    auto issueK = [&](int buf, int m0) {
#pragma unroll
        for (int j = 0; j < 2; ++j) {
            int cid = w * 2 + j;
            int row = cid * 2 + (l >> 5);
            int srcoff = ((l & 31) * 16) ^ ((row & 7) << 4);
            const char* gp = Kzb + (size_t)(m0 + row) * 512 + srcoff;
            __builtin_amdgcn_global_load_lds(
                (const __attribute__((address_space(1))) void*)gp,
                (__attribute__((address_space(3))) void*)(smem + buf * 16384 + cid * 1024),
                16, 0, 0);
        }
    };
    // V tile 16KB: 256 rows x 64B; swizzle ^(((row>>1)&3)<<4) — bits 4-5 only (in-row)
    auto issueV = [&](int slot, int m0) {
#pragma unroll
        for (int j = 0; j < 2; ++j) {
            int cid = w * 2 + j;
            int row = cid * 16 + (l >> 2);
            int srcoff = ((l & 3) * 16) ^ (((row >> 1) & 3) << 4);
            const char* gp = Vzb + (size_t)row * 2048 + (size_t)m0 * 2 + srcoff;
            __builtin_amdgcn_global_load_lds(
                (const __attribute__((address_space(1))) void*)gp,
                (__attribute__((address_space(3))) void*)(smem + 32768 + slot * 16384 + cid * 1024),
                16, 0, 0);
        }
    };

    // QK(t)+exp -> P[par]. sacc: n-row = wn*32+fi*16+g*4+r, m = m0 + wc*16 + c16.
    auto qk_exp = [&](int buf, int par, int m0) {
        const unsigned char* Ks = smem + buf * 16384;
        unsigned char* Ps = smem + 81920 + par * 16384;
        f32x4 sacc[2];
#pragma unroll
        for (int fi = 0; fi < 2; ++fi) sacc[fi] = (f32x4){0.f, 0.f, 0.f, 0.f};
        int mr = wc * 16 + c16;
        __builtin_amdgcn_s_setprio(1);
#pragma unroll
        for (int ks = 0; ks < 8; ++ks) {
            s16x8 kf = *(const s16x8*)(Ks + ((mr * 512 + ks * 64 + g * 16) ^ ((mr & 7) << 4)));
#pragma unroll
            for (int fi = 0; fi < 2; ++fi)
                sacc[fi] = __builtin_amdgcn_mfma_f32_16x16x32_bf16(q[fi][ks], kf, sacc[fi], 0, 0, 0);
        }
        __builtin_amdgcn_s_setprio(0);
        float bet = bs[m0 + wc * 16 + c16];
#pragma unroll
        for (int fi = 0; fi < 2; ++fi)
#pragma unroll
            for (int r = 0; r < 4; ++r) {
                float e = __expf((sacc[fi][r] + bet) * SCALE);
                unsigned short h = f2bf(e);
                int nr = wn * 32 + fi * 16 + g * 4 + r;
                *(unsigned short*)(Ps + ((nr * 128 + (wc * 16 + c16) * 2) ^ ((nr & 7) << 4))) = h;
                rs[fi][r] += bf2f(h);
            }
    };
    // PV(t): O += P[par] · V[slot]
    auto pv = [&](int slot, int par) {
        const unsigned char* Vs = smem + 32768 + slot * 16384;
        const unsigned char* Ps = smem + 81920 + par * 16384;
        s16x8 pa[2];
#pragma unroll
        for (int fi = 0; fi < 2; ++fi) {
            int nr = wn * 32 + fi * 16 + c16;
            pa[fi] = *(const s16x8*)(Ps + ((nr * 128 + g * 16) ^ ((nr & 7) << 4)));
        }
        __builtin_amdgcn_s_setprio(1);
#pragma unroll
        for (int fj = 0; fj < 8; ++fj) {
            int er = wc * 128 + fj * 16 + c16;
            s16x8 vb = *(const s16x8*)(Vs + ((er * 64 + g * 16) ^ (((er >> 1) & 3) << 4)));
#pragma unroll
            for (int fi = 0; fi < 2; ++fi)
                o[fi][fj] = __builtin_amdgcn_mfma_f32_16x16x32_bf16(pa[fi], vb, o[fi][fj], 0, 0, 0);
        }
        __builtin_amdgcn_s_setprio(0);
    };

    // prologue: stage tiles 0,1; compute QK(0)->P[0]
    issueK(0, 0); issueV(0, 0);
    issueK(1, 32); issueV(1, 32);
    __syncthreads();
    qk_exp(0, 0, 0);

    for (int mt = 0; mt < 32; ++mt) {
        __syncthreads();   // publishes P[mt&1]; drains gll issued last interval
        if (mt < 30) {
            issueK(mt & 1, (mt + 2) * 32);          // K[mt&1] held K(mt), consumed last interval
            issueV((mt + 2) % 3, (mt + 2) * 32);    // V slot held V(mt-1), read last interval
        }
        __builtin_amdgcn_sched_barrier(0);
        if (mt < 31) qk_exp((mt + 1) & 1, (mt + 1) & 1, (mt + 1) * 32);
        pv(mt % 3, mt & 1);
    }

    // cross-lane + cross-wave rsum
#pragma unroll
    for (int fi = 0; fi < 2; ++fi)
#pragma unroll
        for (int r = 0; r < 4; ++r) {
            float v = rs[fi][r];
            v += __shfl_xor(v, 1); v += __shfl_xor(v, 2);
            v += __shfl_xor(v, 4); v += __shfl_xor(v, 8);
            if (c16 == 0) rsl[wc * 128 + wn * 32 + fi * 16 + g * 4 + r] = v;
        }
    __syncthreads();
    float* Zb = Z + ((size_t)z * NN + n0) * CC;
#pragma unroll
    for (int fi = 0; fi < 2; ++fi)
#pragma unroll
        for (int r = 0; r < 4; ++r) {
            int nr = wn * 32 + fi * 16 + g * 4 + r;
            float inv = 1.0f / (rsl[nr] + rsl[128 + nr]);
#pragma unroll
            for (int fj = 0; fj < 8; ++fj) {
                int e = wc * 128 + fj * 16 + c16;
                Zb[(size_t)nr * CC + e] += o[fi][fj][r] * inv;
            }
        }
}

// BN stats: per-channel sum and sumsq over B*N rows of Z [B*N][C]
__global__ __launch_bounds__(256) void bn_stats_kernel(const float* __restrict__ Z, float* __restrict__ bn) {
    int blk = blockIdx.x, e = threadIdx.x;
    const float* p = Z + (size_t)blk * 256 * CC + e;
    float s1 = 0.f, s2 = 0.f;
    for (int r = 0; r < 256; ++r) { float v = p[(size_t)r * CC]; s1 += v; s2 += v * v; }
    atomicAdd(&bn[e], s1);
    atomicAdd(&bn[CC + e], s2);
}

// normalize + relu + transpose [B][N][C] -> [B][C][N]
__global__ __launch_bounds__(256) void bn_apply_kernel(const float* __restrict__ Z, const float* __restrict__ bn,
                                                       const float* __restrict__ gamma, const float* __restrict__ beta,
                                                       float* __restrict__ out) {
    int b = blockIdx.z, e0 = blockIdx.y * 32, n0 = blockIdx.x * 32, t = threadIdx.x;
    __shared__ float tile[32][33];
    int c = t & 31, r0 = (t >> 5) * 4;
#pragma unroll
    for (int q = 0; q < 4; ++q)
        tile[r0 + q][c] = Z[((size_t)b * NN + n0 + r0 + q) * CC + e0 + c];
    __syncthreads();
    int n = t & 31, er0 = (t >> 5) * 4;
    const float invcnt = 1.0f / (BB * NN);
#pragma unroll
    for (int q = 0; q < 4; ++q) {
        int e = e0 + er0 + q;
        float mean = bn[e] * invcnt;
        float var = bn[CC + e] * invcnt - mean * mean;
        float rsq = rsqrtf(var + EPSV);
        float v = (tile[n][er0 + q] - mean) * rsq * gamma[e] + beta[e];
        out[((size_t)b * CC + e) * NN + n0 + n] = fmaxf(v, 0.f);
    }
}

extern "C" void kernel_launch(void* const* d_in, const int* in_sizes, int n_in,
                              void* d_out, int out_size, void* d_ws, size_t ws_size,
                              hipStream_t stream) {
    const float* x    = (const float*)d_in[0];
    const float* Wq_s = (const float*)d_in[2];  const float* bq_s = (const float*)d_in[3];
    const float* Wk_s = (const float*)d_in[4];  const float* bk_s = (const float*)d_in[5];
    const float* Wv_s = (const float*)d_in[6];  const float* bv_s = (const float*)d_in[7];
    const float* Wo_s = (const float*)d_in[8];  const float* bo_s = (const float*)d_in[9];
    const float* Wq_g = (const float*)d_in[10]; const float* bq_g = (const float*)d_in[11];
    const float* Wk_g = (const float*)d_in[12]; const float* bk_g = (const float*)d_in[13];
    const float* Wv_g = (const float*)d_in[14]; const float* bv_g = (const float*)d_in[15];
    const float* Wo_g = (const float*)d_in[16]; const float* bo_g = (const float*)d_in[17];
    const float* Wf   = (const float*)d_in[18]; const float* bf   = (const float*)d_in[19];
    const float* gamma = (const float*)d_in[20]; const float* beta = (const float*)d_in[21];

    float* ws    = (float*)d_ws;
    float* mu    = ws + OFF_MU;
    float* score = ws + OFF_SCORE;
    int*   idx_s = (int*)(ws + OFF_IDX);
    int*   idx_g = idx_s + BB * MM;
    float* WoWv  = ws + OFF_U;             // f32 scratch (per branch, serial reuse)
    float* Wf12  = ws + OFF_WF12;
    float* bvz   = ws + OFF_BVZ;
    float* bz    = ws + OFF_BZ;
    float* uvec  = ws + OFF_MU;            // mu dead after transpose_score; 257 floats
    float* b2    = ws + OFF_MU + 512;      // 256 floats
    float* wob   = ws + OFF_MU + 1024;     // 256 floats
    float* betaA = ws + OFF_SCORE;         // score dead after select; [B][M] floats
    unsigned short* Wf12_16 = (unsigned short*)(ws + OFF_W16);
    unsigned short* W2_16   = Wf12_16 + 65536;
    unsigned short* Wvz16   = W2_16 + 65536;
    unsigned short* Xg16 = (unsigned short*)(ws + OFF_XG);
    unsigned short* K16  = (unsigned short*)(ws + OFF_K16);
    unsigned short* Vt16 = (unsigned short*)(ws + OFF_VT16);
    float* Z     = ws + OFF_Z;
    float* bn    = ws + OFF_BN;
    // d_out doubles as scratch: second half holds xT16 (dead before bn_apply writes)
    unsigned short* xT16 = (unsigned short*)d_out + (size_t)BB * NN * CC;

    zero_bn_kernel<<<1, 256, 0, stream>>>(bn);
    mean_kernel<<<dim3(CC, BB), 256, 0, stream>>>(x, mu);
    zero_rsum_kernel<<<BB * NN / 256, 256, 0, stream>>>(score);
    transpose_score_kernel<<<dim3(NN / 32, CC / 32, BB), 256, 0, stream>>>(x, mu, xT16, score);
    select_kernel<<<BB, 1024, 0, stream>>>(score, idx_s, idx_g);
    wf12_kernel<<<CC, 256, 0, stream>>>(Wf, Wf12);
    bz_kernel<<<1, 256, 0, stream>>>(Wf, bf, bo_s, bo_g, bz);
    conv_bf16_kernel<<<64, 256, 0, stream>>>(Wf12, Wf12_16);
    // Z = xT @ Wf12^T + bz  (residual x through both conv halves)
    gemm_bt<0><<<dim3(512, 2, 1), 256, 0, stream>>>(xT16, 0, Wf12_16, 0, bz, Z, 0, CC);

    for (int br = 0; br < 2; ++br) {
        const float* Wo = br ? Wo_g : Wo_s;
        const float* Wv = br ? Wv_g : Wv_s;  const float* bv = br ? bv_g : bv_s;
        const float* Wk = br ? Wk_g : Wk_s;  const float* bk = br ? bk_g : bk_s;
        const float* Wq = br ? Wq_g : Wq_s;  const float* bq = br ? bq_g : bq_s;
        int* idx = br ? idx_g : idx_s;
        int aoff = br ? CC : 0;
        // consolidated precompute: WoWv, W2->bf16, wob/u/b2  then  Wvz->bf16 + bvz
        prep1_kernel<<<dim3(CC, 3), 256, 0, stream>>>(Wo, Wv, Wq, Wk, bq, bk, bv,
                                                      WoWv, W2_16, wob, uvec, b2);
        prep2_kernel<<<CC, 256, 0, stream>>>(Wf, aoff, WoWv, wob, Wvz16, bvz);
        // gather context rows once
        gather_kernel<<<BB * MM / 4, 256, 0, stream>>>(xT16, idx, Xg16);
        // K'' = Xg @ W2^T + b2 ; beta = Xg·u + bq·bk ; Vt = Wvz @ Xg^T + bvz
        gemm_bt<1><<<dim3(BB * MM / 128, 2, 1), 256, 0, stream>>>(Xg16, 0, W2_16, 0, b2, K16, 0, CC);
        beta_kernel<<<BB * MM / 4, 256, 0, stream>>>(Xg16, uvec, betaA);
        gemm_bt<2><<<dim3(2, 8, BB), 256, 0, stream>>>(Wvz16, 0, Xg16, (size_t)MM * CC, bvz,
                                                       Vt16, (size_t)CC * MM, MM);

        // fused flash attention: Z += softmax((xT·K''^T + beta)/16)·V
        fused_attn<<<dim3(NN / 128, 1, BB), 512, 119808, stream>>>(xT16, K16, Vt16, betaA, Z);
    }

    bn_stats_kernel<<<BB * NN / 256, 256, 0, stream>>>(Z, bn);
    bn_apply_kernel<<<dim3(NN / 32, CC / 32, BB), 256, 0, stream>>>(Z, bn, gamma, beta, (float*)d_out);
}